// Round 13
// baseline (33.751 us; speedup 1.0000x reference)
//
#include <hip/hip_runtime.h>
#include <hip/hip_fp16.h>
#include <math.h>

constexpr int B    = 512;
constexpr int NIN  = 1024;
constexpr int NK   = 128;
constexpr int DK   = 5;
constexpr int NF   = NK * DK;     // 640 flattened kernel columns
constexpr int NOUT = NIN + NK;    // 1152
constexpr int SPLITK = 8;         // K chunks (128 each)
constexpr int LDA = 136;          // LDS row stride in halves (128 + 8 pad)
#define LOG2E 1.44269504088896f

typedef _Float16 f16x4 __attribute__((ext_vector_type(4)));
typedef _Float16 f16x8 __attribute__((ext_vector_type(8)));
typedef float    f32x4 __attribute__((ext_vector_type(4)));

// ---------------------------------------------------------------------------
// MEASUREMENT ROUND: kernels are byte-identical to R10 (best: 24.0 us).
// Launch sequence gemm x3 + pairwise x1 (idempotent, deterministic).
// dur - 24.0 = 2*gemm_warm + 2*gap  ->  attributes the ~20 us kernel time.
// ---------------------------------------------------------------------------

// ---------------------------------------------------------------------------
// Kernel 1: split-K MFMA GEMM, 32n x 64b x 128k tiles, f16 partial output.
//   grid 1280 = (20 n-tiles x 8 b-tiles) x 8 z; 256 thr = 4 waves.
// ---------------------------------------------------------------------------
__global__ __launch_bounds__(256) void gemm_kernel(
        const float* __restrict__ x,       // [512][1024]
        const float* __restrict__ theta,   // [1024][640]
        __half* __restrict__ actvP16,      // [8][640][512]
        float* __restrict__ ps) {          // [8][640]
    __shared__ _Float16 Ath[32 * LDA];     // theta^T tile [n][k]
    __shared__ _Float16 Bxh[64 * LDA];     // x tile [b][k]
    __shared__ float    red2[32][33];

    const int t    = threadIdx.x;
    const int tile = blockIdx.x >> 3;
    const int z    = blockIdx.x & 7;
    const int nt   = tile >> 3;            // 0..19
    const int bt   = tile & 7;             // 0..7
    const int n0   = nt * 32;
    const int b0   = bt * 64;
    const bool do_ps = (bt == 0);
    const int kw   = z * 128;

    const int kq = t >> 3;                 // 0..31, k-rows kq*4..+3
    const int nc = (t & 7) * 4;            // 4 n-cols
    float4 tv0 = *(const float4*)&theta[(kw + kq*4 + 0) * NF + n0 + nc];
    float4 tv1 = *(const float4*)&theta[(kw + kq*4 + 1) * NF + n0 + nc];
    float4 tv2 = *(const float4*)&theta[(kw + kq*4 + 2) * NF + n0 + nc];
    float4 tv3 = *(const float4*)&theta[(kw + kq*4 + 3) * NF + n0 + nc];

    const int br = t >> 2;                 // 0..63
    const int ki = t & 3;
    float4 xv[8];
    #pragma unroll
    for (int i = 0; i < 8; ++i)
        xv[i] = *(const float4*)&x[(b0 + br) * NIN + kw + (ki + i * 4) * 4];

    if (do_ps) {
        red2[kq][nc + 0] = tv0.x*tv0.x + tv1.x*tv1.x + tv2.x*tv2.x + tv3.x*tv3.x;
        red2[kq][nc + 1] = tv0.y*tv0.y + tv1.y*tv1.y + tv2.y*tv2.y + tv3.y*tv3.y;
        red2[kq][nc + 2] = tv0.z*tv0.z + tv1.z*tv1.z + tv2.z*tv2.z + tv3.z*tv3.z;
        red2[kq][nc + 3] = tv0.w*tv0.w + tv1.w*tv1.w + tv2.w*tv2.w + tv3.w*tv3.w;
    }

    {
        f16x4 h;
        h[0]=(_Float16)tv0.x; h[1]=(_Float16)tv1.x; h[2]=(_Float16)tv2.x; h[3]=(_Float16)tv3.x;
        *(f16x4*)&Ath[(nc + 0) * LDA + kq * 4] = h;
        h[0]=(_Float16)tv0.y; h[1]=(_Float16)tv1.y; h[2]=(_Float16)tv2.y; h[3]=(_Float16)tv3.y;
        *(f16x4*)&Ath[(nc + 1) * LDA + kq * 4] = h;
        h[0]=(_Float16)tv0.z; h[1]=(_Float16)tv1.z; h[2]=(_Float16)tv2.z; h[3]=(_Float16)tv3.z;
        *(f16x4*)&Ath[(nc + 2) * LDA + kq * 4] = h;
        h[0]=(_Float16)tv0.w; h[1]=(_Float16)tv1.w; h[2]=(_Float16)tv2.w; h[3]=(_Float16)tv3.w;
        *(f16x4*)&Ath[(nc + 3) * LDA + kq * 4] = h;
    }
    #pragma unroll
    for (int i = 0; i < 8; ++i) {
        f16x4 h;
        h[0] = (_Float16)xv[i].x;  h[1] = (_Float16)xv[i].y;
        h[2] = (_Float16)xv[i].z;  h[3] = (_Float16)xv[i].w;
        *(f16x4*)&Bxh[br * LDA + (ki + i * 4) * 4] = h;
    }
    __syncthreads();

    const int w   = t >> 6;
    const int l   = t & 63;
    const int r16 = l & 15;
    const int kg  = l >> 4;

    f32x4 acc0 = {0.f,0.f,0.f,0.f}, acc1 = {0.f,0.f,0.f,0.f};
    #pragma unroll
    for (int ks = 0; ks < 4; ++ks) {
        const f16x8 bv  = *(const f16x8*)&Bxh[(w*16 + r16)*LDA + ks*32 + kg*8];
        const f16x8 av0 = *(const f16x8*)&Ath[( 0 + r16)*LDA + ks*32 + kg*8];
        const f16x8 av1 = *(const f16x8*)&Ath[(16 + r16)*LDA + ks*32 + kg*8];
        acc0 = __builtin_amdgcn_mfma_f32_16x16x32_f16(av0, bv, acc0, 0, 0, 0);
        acc1 = __builtin_amdgcn_mfma_f32_16x16x32_f16(av1, bv, acc1, 0, 0, 0);
    }

    {
        __half* dst = actvP16 + (size_t)z * NF * B
                    + (size_t)(n0 + kg*4) * B + b0 + w*16 + r16;
        #pragma unroll
        for (int j = 0; j < 4; ++j) {
            dst[j*B]          = __float2half(acc0[j]);
            dst[(16 + j) * B] = __float2half(acc1[j]);
        }
    }
    if (do_ps) {
        __syncthreads();
        if (t < 32) {
            float tot = 0.f;
            #pragma unroll
            for (int rr = 0; rr < 32; ++rr) tot += red2[rr][t];
            ps[z * NF + n0 + t] = tot;
        }
    }
}

// ---------------------------------------------------------------------------
// Kernel 2: pairwise finish with integrated split-K reduce + scale.
// grid (128 k, 4 e) x 512 thr — identical to R10.
// ---------------------------------------------------------------------------
__global__ __launch_bounds__(512) void pairwise_kernel(
        const __half* __restrict__ actvP16,// [8][640][512]
        const float* __restrict__ ps,      // [8][640]
        const float* __restrict__ lws,     // [640]
        const float* __restrict__ bias,    // [128]
        const float* __restrict__ x,       // [512][1024]
        float* __restrict__ out) {         // [512][1152]
    __shared__ __half a16s[DK * B];        // 5120 B
    __shared__ float  red[8 * 128];
    __shared__ float  s_sh[DK];
    __shared__ float  red_ps[DK * SPLITK];

    const int k = blockIdx.x;
    const int e = blockIdx.y;              // b-quarter (0..3)
    const int t = threadIdx.x;

    if (t >= 256) {
        const int u = t - 256;
        const int row = k * 4 + e;
        ((float4*)out)[row * (NOUT/4) + u] = ((const float4*)x)[row * (NIN/4) + u];
    }
    if (t >= 448 && t < 448 + DK * SPLITK) {
        const int u = t - 448;
        red_ps[u] = ps[(u / DK) * NF + k * DK + (u % DK)];
    }

    const size_t slab = (size_t)k * DK * B;
    float accf[8];
    #pragma unroll
    for (int i = 0; i < 8; ++i) accf[i] = 0.f;
    if (t < 320) {
        #pragma unroll
        for (int z = 0; z < SPLITK; ++z) {
            const f16x8 v = *(const f16x8*)(actvP16 + (size_t)z * NF * B + slab + t * 8);
            #pragma unroll
            for (int i = 0; i < 8; ++i) accf[i] += (float)v[i];
        }
    }
    __syncthreads();
    if (t < DK) {
        float sum = 0.f;
        #pragma unroll
        for (int c = 0; c < SPLITK; ++c) sum += red_ps[c * DK + t];
        s_sh[t] = __expf(lws[k * DK + t]) * rsqrtf(sum) * LOG2E;
    }
    __syncthreads();
    if (t < 320) {
        const float s = s_sh[t >> 6];      // d = t/64, wave-uniform
        f16x8 h;
        #pragma unroll
        for (int i = 0; i < 8; ++i) h[i] = (_Float16)(accf[i] * s);
        *(f16x8*)&a16s[t * 8] = h;
    }
    __syncthreads();

    const int g  = t >> 6;                 // wave-uniform b' eighth (0..7)
    const int r  = t & 63;
    const int ba = e * 128 + r;
    const int bb = ba + 64;

    __half2 A2[DK], B2[DK];
    #pragma unroll
    for (int d = 0; d < DK; ++d) {
        A2[d] = __half2half2(a16s[d * B + ba]);
        B2[d] = __half2half2(a16s[d * B + bb]);
    }

    float accA = 0.f, accB = 0.f;
    const int bp0 = g * 64;

    union W8 { f16x8 v; __half2 h[4]; };
    typedef _Float16 f16x2v __attribute__((ext_vector_type(2)));
    union HV { __half2 h; f16x2v v; };
    const HV ones = {__half2half2(__float2half(1.0f))};

    #pragma unroll 2
    for (int m = 0; m < 8; ++m) {
        const int bp = bp0 + m * 8;        // wave-uniform -> LDS b128 broadcast
        W8 w0, w1, w2, w3, w4;
        w0.v = *(const f16x8*)&a16s[0*B + bp];
        w1.v = *(const f16x8*)&a16s[1*B + bp];
        w2.v = *(const f16x8*)&a16s[2*B + bp];
        w3.v = *(const f16x8*)&a16s[3*B + bp];
        w4.v = *(const f16x8*)&a16s[4*B + bp];
        #pragma unroll
        for (int c = 0; c < 4; ++c) {
            __half2 dA = __habs2(__hsub2(A2[0], w0.h[c]));
            dA = __hadd2(dA, __habs2(__hsub2(A2[1], w1.h[c])));
            dA = __hadd2(dA, __habs2(__hsub2(A2[2], w2.h[c])));
            dA = __hadd2(dA, __habs2(__hsub2(A2[3], w3.h[c])));
            dA = __hadd2(dA, __habs2(__hsub2(A2[4], w4.h[c])));
            HV eA; eA.h = h2exp2(__hneg2(dA));
            __half2 dB = __habs2(__hsub2(B2[0], w0.h[c]));
            dB = __hadd2(dB, __habs2(__hsub2(B2[1], w1.h[c])));
            dB = __hadd2(dB, __habs2(__hsub2(B2[2], w2.h[c])));
            dB = __hadd2(dB, __habs2(__hsub2(B2[3], w3.h[c])));
            dB = __hadd2(dB, __habs2(__hsub2(B2[4], w4.h[c])));
            HV eB; eB.h = h2exp2(__hneg2(dB));
#if __has_builtin(__builtin_amdgcn_fdot2)
            accA = __builtin_amdgcn_fdot2(eA.v, ones.v, accA, false);
            accB = __builtin_amdgcn_fdot2(eB.v, ones.v, accB, false);
#else
            accA += __low2float(eA.h) + __high2float(eA.h);
            accB += __low2float(eB.h) + __high2float(eB.h);
#endif
        }
    }
    red[g * 128 + r]      = accA;
    red[g * 128 + 64 + r] = accB;
    __syncthreads();
    if (t < 128) {
        float f = -1.0f + bias[k];
        #pragma unroll
        for (int gg = 0; gg < 8; ++gg) f += red[gg * 128 + t];
        out[(e * 128 + t) * NOUT + NIN + k] = f;
    }
}

// ---------------------------------------------------------------------------
extern "C" void kernel_launch(void* const* d_in, const int* in_sizes, int n_in,
                              void* d_out, int out_size, void* d_ws, size_t ws_size,
                              hipStream_t stream) {
    const float* x     = (const float*)d_in[0];   // [512,1024]
    const float* theta = (const float*)d_in[1];   // [1024,128,5]
    const float* lws   = (const float*)d_in[2];   // [128,5]
    const float* bias  = (const float*)d_in[3];   // [128]
    float* out = (float*)d_out;                   // [512,1152]

    // ws layout: ps @0 (64KB pad), actvP16 f16 8 slabs @64KB (5.24MB)
    char* wsb = (char*)d_ws;
    float*  ps       = (float*)wsb;
    __half* actvP16  = (__half*)(wsb + (64 << 10));

    // ---- A/B attribution: gemm x3 (idempotent) + pairwise x1 ----
    gemm_kernel<<<dim3(1280), 256, 0, stream>>>(x, theta, actvP16, ps);
    gemm_kernel<<<dim3(1280), 256, 0, stream>>>(x, theta, actvP16, ps);
    gemm_kernel<<<dim3(1280), 256, 0, stream>>>(x, theta, actvP16, ps);
    pairwise_kernel<<<dim3(NK, 4), 512, 0, stream>>>(actvP16, ps, lws, bias, x, out);
}

// Round 14
// 24.899 us; speedup vs baseline: 1.3555x; 1.3555x over previous
//
#include <hip/hip_runtime.h>
#include <hip/hip_fp16.h>
#include <math.h>

constexpr int B    = 512;
constexpr int NIN  = 1024;
constexpr int NK   = 128;
constexpr int DK   = 5;
constexpr int NF   = NK * DK;     // 640 flattened kernel columns
constexpr int NOUT = NIN + NK;    // 1152
constexpr int SPLITK = 8;         // K chunks (128 each)
constexpr int LDA = 136;          // LDS row stride in halves (128 + 8 pad)
#define LOG2E 1.44269504088896f

typedef _Float16 f16x4 __attribute__((ext_vector_type(4)));
typedef _Float16 f16x8 __attribute__((ext_vector_type(8)));
typedef float    f32x4 __attribute__((ext_vector_type(4)));

// ---------------------------------------------------------------------------
// Kernel 1: split-K MFMA GEMM — byte-identical to R10 (gemm ≈ 2.5-4 µs).
// ---------------------------------------------------------------------------
__global__ __launch_bounds__(256) void gemm_kernel(
        const float* __restrict__ x,       // [512][1024]
        const float* __restrict__ theta,   // [1024][640]
        __half* __restrict__ actvP16,      // [8][640][512]
        float* __restrict__ ps) {          // [8][640]
    __shared__ _Float16 Ath[32 * LDA];     // theta^T tile [n][k]
    __shared__ _Float16 Bxh[64 * LDA];     // x tile [b][k]
    __shared__ float    red2[32][33];

    const int t    = threadIdx.x;
    const int tile = blockIdx.x >> 3;
    const int z    = blockIdx.x & 7;
    const int nt   = tile >> 3;            // 0..19
    const int bt   = tile & 7;             // 0..7
    const int n0   = nt * 32;
    const int b0   = bt * 64;
    const bool do_ps = (bt == 0);
    const int kw   = z * 128;

    const int kq = t >> 3;                 // 0..31, k-rows kq*4..+3
    const int nc = (t & 7) * 4;            // 4 n-cols
    float4 tv0 = *(const float4*)&theta[(kw + kq*4 + 0) * NF + n0 + nc];
    float4 tv1 = *(const float4*)&theta[(kw + kq*4 + 1) * NF + n0 + nc];
    float4 tv2 = *(const float4*)&theta[(kw + kq*4 + 2) * NF + n0 + nc];
    float4 tv3 = *(const float4*)&theta[(kw + kq*4 + 3) * NF + n0 + nc];

    const int br = t >> 2;                 // 0..63
    const int ki = t & 3;
    float4 xv[8];
    #pragma unroll
    for (int i = 0; i < 8; ++i)
        xv[i] = *(const float4*)&x[(b0 + br) * NIN + kw + (ki + i * 4) * 4];

    if (do_ps) {
        red2[kq][nc + 0] = tv0.x*tv0.x + tv1.x*tv1.x + tv2.x*tv2.x + tv3.x*tv3.x;
        red2[kq][nc + 1] = tv0.y*tv0.y + tv1.y*tv1.y + tv2.y*tv2.y + tv3.y*tv3.y;
        red2[kq][nc + 2] = tv0.z*tv0.z + tv1.z*tv1.z + tv2.z*tv2.z + tv3.z*tv3.z;
        red2[kq][nc + 3] = tv0.w*tv0.w + tv1.w*tv1.w + tv2.w*tv2.w + tv3.w*tv3.w;
    }

    {
        f16x4 h;
        h[0]=(_Float16)tv0.x; h[1]=(_Float16)tv1.x; h[2]=(_Float16)tv2.x; h[3]=(_Float16)tv3.x;
        *(f16x4*)&Ath[(nc + 0) * LDA + kq * 4] = h;
        h[0]=(_Float16)tv0.y; h[1]=(_Float16)tv1.y; h[2]=(_Float16)tv2.y; h[3]=(_Float16)tv3.y;
        *(f16x4*)&Ath[(nc + 1) * LDA + kq * 4] = h;
        h[0]=(_Float16)tv0.z; h[1]=(_Float16)tv1.z; h[2]=(_Float16)tv2.z; h[3]=(_Float16)tv3.z;
        *(f16x4*)&Ath[(nc + 2) * LDA + kq * 4] = h;
        h[0]=(_Float16)tv0.w; h[1]=(_Float16)tv1.w; h[2]=(_Float16)tv2.w; h[3]=(_Float16)tv3.w;
        *(f16x4*)&Ath[(nc + 3) * LDA + kq * 4] = h;
    }
    #pragma unroll
    for (int i = 0; i < 8; ++i) {
        f16x4 h;
        h[0] = (_Float16)xv[i].x;  h[1] = (_Float16)xv[i].y;
        h[2] = (_Float16)xv[i].z;  h[3] = (_Float16)xv[i].w;
        *(f16x4*)&Bxh[br * LDA + (ki + i * 4) * 4] = h;
    }
    __syncthreads();

    const int w   = t >> 6;
    const int l   = t & 63;
    const int r16 = l & 15;
    const int kg  = l >> 4;

    f32x4 acc0 = {0.f,0.f,0.f,0.f}, acc1 = {0.f,0.f,0.f,0.f};
    #pragma unroll
    for (int ks = 0; ks < 4; ++ks) {
        const f16x8 bv  = *(const f16x8*)&Bxh[(w*16 + r16)*LDA + ks*32 + kg*8];
        const f16x8 av0 = *(const f16x8*)&Ath[( 0 + r16)*LDA + ks*32 + kg*8];
        const f16x8 av1 = *(const f16x8*)&Ath[(16 + r16)*LDA + ks*32 + kg*8];
        acc0 = __builtin_amdgcn_mfma_f32_16x16x32_f16(av0, bv, acc0, 0, 0, 0);
        acc1 = __builtin_amdgcn_mfma_f32_16x16x32_f16(av1, bv, acc1, 0, 0, 0);
    }

    {
        __half* dst = actvP16 + (size_t)z * NF * B
                    + (size_t)(n0 + kg*4) * B + b0 + w*16 + r16;
        #pragma unroll
        for (int j = 0; j < 4; ++j) {
            dst[j*B]          = __float2half(acc0[j]);
            dst[(16 + j) * B] = __float2half(acc1[j]);
        }
    }
    if (do_ps) {
        __syncthreads();
        if (t < 32) {
            float tot = 0.f;
            #pragma unroll
            for (int rr = 0; rr < 32; ++rr) tot += red2[rr][t];
            ps[z * NF + n0 + t] = tot;
        }
    }
}

// ---------------------------------------------------------------------------
// Kernel 2: pairwise finish — SAME math as R10, 2x the TLP.
// grid (128 k, 4 e) x 1024 thr, __launch_bounds__(1024, 8):
//   2 blocks/CU co-resident -> 32 waves/CU = 8 waves/SIMD (was 4).
// thread: row ba = e*128 + (t&127); b'-eighth g = t>>7 (64 b' each).
// ---------------------------------------------------------------------------
__global__ __launch_bounds__(1024, 8) void pairwise_kernel(
        const __half* __restrict__ actvP16,// [8][640][512]
        const float* __restrict__ ps,      // [8][640]
        const float* __restrict__ lws,     // [640]
        const float* __restrict__ bias,    // [128]
        const float* __restrict__ x,       // [512][1024]
        float* __restrict__ out) {         // [512][1152]
    __shared__ __half a16s[DK * B];        // 5120 B
    __shared__ float  red[8 * 128];        // 4096 B
    __shared__ float  s_sh[DK];
    __shared__ float  red_ps[DK * SPLITK];

    const int k = blockIdx.x;
    const int e = blockIdx.y;              // b-quarter (0..3)
    const int t = threadIdx.x;

    // fused x passthrough: threads [512,768) copy row k*4+e
    if (t >= 512 && t < 768) {
        const int u = t - 512;
        const int row = k * 4 + e;
        ((float4*)out)[row * (NOUT/4) + u] = ((const float4*)x)[row * (NIN/4) + u];
    }
    if (t >= 768 && t < 768 + DK * SPLITK) {
        const int u = t - 768;
        red_ps[u] = ps[(u / DK) * NF + k * DK + (u % DK)];
    }

    // ---- split-K reduce into f32 regs: unit t = 8 halves (t < 320) ----
    const size_t slab = (size_t)k * DK * B;
    float accf[8];
    #pragma unroll
    for (int i = 0; i < 8; ++i) accf[i] = 0.f;
    if (t < 320) {
        #pragma unroll
        for (int z = 0; z < SPLITK; ++z) {
            const f16x8 v = *(const f16x8*)(actvP16 + (size_t)z * NF * B + slab + t * 8);
            #pragma unroll
            for (int i = 0; i < 8; ++i) accf[i] += (float)v[i];
        }
    }
    __syncthreads();
    if (t < DK) {
        float sum = 0.f;
        #pragma unroll
        for (int c = 0; c < SPLITK; ++c) sum += red_ps[c * DK + t];
        s_sh[t] = __expf(lws[k * DK + t]) * rsqrtf(sum) * LOG2E;
    }
    __syncthreads();
    if (t < 320) {
        const float s = s_sh[t >> 6];      // d = t/64, wave-uniform
        f16x8 h;
        #pragma unroll
        for (int i = 0; i < 8; ++i) h[i] = (_Float16)(accf[i] * s);
        *(f16x8*)&a16s[t * 8] = h;
    }
    __syncthreads();

    const int g  = t >> 7;                 // wave-pair-uniform b'-eighth (0..7)
    const int r  = t & 127;
    const int ba = e * 128 + r;

    __half2 A2[DK];
    #pragma unroll
    for (int d = 0; d < DK; ++d) A2[d] = __half2half2(a16s[d * B + ba]);

    float acc = 0.f;
    const int bp0 = g * 64;

    union W8 { f16x8 v; __half2 h[4]; };
    typedef _Float16 f16x2v __attribute__((ext_vector_type(2)));
    union HV { __half2 h; f16x2v v; };
    const HV ones = {__half2half2(__float2half(1.0f))};

    #pragma unroll 2
    for (int m = 0; m < 8; ++m) {
        const int bp = bp0 + m * 8;        // wave-uniform -> LDS b128 broadcast
        W8 w0, w1, w2, w3, w4;
        w0.v = *(const f16x8*)&a16s[0*B + bp];
        w1.v = *(const f16x8*)&a16s[1*B + bp];
        w2.v = *(const f16x8*)&a16s[2*B + bp];
        w3.v = *(const f16x8*)&a16s[3*B + bp];
        w4.v = *(const f16x8*)&a16s[4*B + bp];
        #pragma unroll
        for (int c = 0; c < 4; ++c) {
            __half2 dA = __habs2(__hsub2(A2[0], w0.h[c]));
            dA = __hadd2(dA, __habs2(__hsub2(A2[1], w1.h[c])));
            dA = __hadd2(dA, __habs2(__hsub2(A2[2], w2.h[c])));
            dA = __hadd2(dA, __habs2(__hsub2(A2[3], w3.h[c])));
            dA = __hadd2(dA, __habs2(__hsub2(A2[4], w4.h[c])));
            HV eA; eA.h = h2exp2(__hneg2(dA));
#if __has_builtin(__builtin_amdgcn_fdot2)
            acc = __builtin_amdgcn_fdot2(eA.v, ones.v, acc, false);
#else
            acc += __low2float(eA.h) + __high2float(eA.h);
#endif
        }
    }
    red[g * 128 + r] = acc;
    __syncthreads();
    if (t < 128) {
        float f = -1.0f + bias[k];
        #pragma unroll
        for (int gg = 0; gg < 8; ++gg) f += red[gg * 128 + t];
        out[(e * 128 + t) * NOUT + NIN + k] = f;
    }
}

// ---------------------------------------------------------------------------
extern "C" void kernel_launch(void* const* d_in, const int* in_sizes, int n_in,
                              void* d_out, int out_size, void* d_ws, size_t ws_size,
                              hipStream_t stream) {
    const float* x     = (const float*)d_in[0];   // [512,1024]
    const float* theta = (const float*)d_in[1];   // [1024,128,5]
    const float* lws   = (const float*)d_in[2];   // [128,5]
    const float* bias  = (const float*)d_in[3];   // [128]
    float* out = (float*)d_out;                   // [512,1152]

    // ws layout: ps @0 (64KB pad), actvP16 f16 8 slabs @64KB (5.24MB)
    char* wsb = (char*)d_ws;
    float*  ps       = (float*)wsb;
    __half* actvP16  = (__half*)(wsb + (64 << 10));

    gemm_kernel<<<dim3(1280), 256, 0, stream>>>(x, theta, actvP16, ps);
    pairwise_kernel<<<dim3(NK, 4), 1024, 0, stream>>>(actvP16, ps, lws, bias, x, out);
}